// Round 6
// baseline (606.309 us; speedup 1.0000x reference)
//
#include <hip/hip_runtime.h>
#include <hip/hip_bf16.h>
#include <math.h>

// Problem constants
//  D=2048, H=16, KVH=8, DH=128, B=4, L=2048, T=8192, C=64, chunks=32, chains=B*H=64
#define RSQRT_DH 0.08838834764831845f

typedef __attribute__((ext_vector_type(8))) short short8;
typedef __attribute__((ext_vector_type(4))) float floatx4;

#define BAR() do { asm volatile("" ::: "memory"); __builtin_amdgcn_s_barrier(); asm volatile("" ::: "memory"); } while (0)
#define MFMA16(a, b, c) __builtin_amdgcn_mfma_f32_16x16x32_bf16((a), (b), (c), 0, 0, 0)

static __device__ __forceinline__ float bf2f(unsigned short u) {
  return __uint_as_float(((unsigned int)u) << 16);
}
static __device__ __forceinline__ unsigned short f2bf(float f) {
  unsigned int x = __float_as_uint(f);
  return (unsigned short)((x + 0x7fffu + ((x >> 16) & 1u)) >> 16);
}
static __device__ __forceinline__ ushort4 f4bf(float a, float b, float c, float d) {
  ushort4 r; r.x = f2bf(a); r.y = f2bf(b); r.z = f2bf(c); r.w = f2bf(d); return r;
}
// 8-byte-aligned LDS load of 8 bf16 (for stride-76 buffers)
static __device__ __forceinline__ short8 ld8u(const unsigned short* p) {
  short4 a = *(const short4*)p;
  short4 b = *(const short4*)(p + 4);
  short8 r;
  r[0] = a.x; r[1] = a.y; r[2] = a.z; r[3] = a.w;
  r[4] = b.x; r[5] = b.y; r[6] = b.z; r[7] = b.w;
  return r;
}

// ---------------- K0: fp32 -> bf16 convert (hidden_states) ----------------
__launch_bounds__(256)
__global__ void k_cvt(const float* __restrict__ in, unsigned short* __restrict__ out, int n4) {
  int i = blockIdx.x * 256 + threadIdx.x;
  if (i >= n4) return;
  float4 v = ((const float4*)in)[i];
  ((ushort4*)out)[i] = f4bf(v.x, v.y, v.z, v.w);
}

// ---------------- K1: W (2048 x 4096 f32) -> Wt (4096 x 2048 bf16), transposed
__launch_bounds__(256)
__global__ void k_cvt_wt(const float* __restrict__ W, unsigned short* __restrict__ Wt) {
  __shared__ float tile[32][33];
  int t = threadIdx.x;
  int c = t & 31, r = t >> 5;            // r in 0..7
  int bx = blockIdx.x, by = blockIdx.y;  // bx: n-tile, by: k-tile
#pragma unroll
  for (int j = 0; j < 4; ++j)
    tile[r + j * 8][c] = W[(size_t)(by * 32 + r + j * 8) * 4096 + bx * 32 + c];
  __syncthreads();
#pragma unroll
  for (int j = 0; j < 4; ++j)
    Wt[(size_t)(bx * 32 + r + j * 8) * 2048 + by * 32 + c] = f2bf(tile[c][r + j * 8]);
}

// ---------------- K2: bf16 MFMA GEMM, m201-style 4-phase BK=64 schedule
//  M=8192 N=4096 K=2048, fused activations. 512 threads = 8 waves (2M x 4N),
//  per-wave 128x64 out (acc[8][4]). 2 LDS dbufs x (A 32KB + B 32KB) = 128 KB.
//  Per K-tile (BK=64): 4 phases, each {ds_read subtile | 0-4 global_load_lds}
//  -> BAR -> lgkmcnt(0) -> setprio(1) -> 16 MFMA (one C-quadrant) -> BAR.
//  Stage tile t+1 during tile t (A halves in P1, B halves in P2); vmcnt(4) at
//  P3, vmcnt(0) at P4 (youngest stage >=1.5 phases old -> no stall; all of
//  tile t+1 resident before its P1 reads). Round-5's coarse 2-phase lockstep
//  anti-phased the LDS and MFMA pipes (MfmaUtil 25%); the fine per-quadrant
//  interleave lets waves' staggered lgkm completion overlap the two pipes.
//  Bank swizzle: LDS row 128B, 8 slots of 16B; phys slot = logical ^ (row&7)
//  (both sides: pre-swizzled global source + swizzled ds_read; uniform
//  8 lanes/bank = conflict-free, measured 0 in rounds 2-5).
//  Epilogue: LDS-staged full-line stores (round-4: WRITE_SIZE 360->96MB).
__launch_bounds__(512, 2)
__global__ void k_gemm(const unsigned short* __restrict__ A,
                       const unsigned short* __restrict__ Bt,
                       const float* __restrict__ bias,
                       unsigned short* __restrict__ qb,
                       unsigned short* __restrict__ kb,
                       unsigned short* __restrict__ vb,
                       float* __restrict__ gf) {
  __shared__ unsigned short lds[65536];  // 128 KiB
  char* lb = (char*)lds;

  const int tid = threadIdx.x;
  const int w = tid >> 6, l = tid & 63;
  const int wm = w >> 2, wn = w & 3;
  const int lr = l & 15, quad = l >> 4;

  // XCD-aware chunking: 512 blocks, id%8 = XCD, 8bm x 8bn rectangle per XCD.
  const int id = blockIdx.x;
  const int x = id & 7, loc = id >> 3;
  const int bm = (x >> 1) * 8 + (loc >> 3);   // 0..31
  const int bn = (x & 1) * 8 + (loc & 7);     // 0..15
  const int m0 = bm * 256, n0 = bn * 256;

  // Staging: one global_load_lds issue = 512 threads x 16B = 8KB = 64 rows x 128B.
  // thread tid -> in-issue row tid>>3, LDS slot tid&7; global slot = (tid&7)^(row&7).
  const int srow = tid >> 3;                       // 0..63
  const int sslot = (tid & 7) ^ (srow & 7);
  const unsigned short* agp = A + (size_t)(m0 + srow) * 2048 + sslot * 8;
  const unsigned short* bgp = Bt + (size_t)(n0 + srow) * 2048 + sslot * 8;

  // LDS byte layout: dbuf d: d*65536; A-half h at +h*16384; B-half h at +32768+h*16384.
  auto stA = [&](int d, int h, int s, int kt) {
    __builtin_amdgcn_global_load_lds(
        (const __attribute__((address_space(1))) void*)(agp + (size_t)(h * 128 + s * 64) * 2048 + kt * 64),
        (__attribute__((address_space(3))) void*)(lb + d * 65536 + h * 16384 + s * 8192 + tid * 16),
        16, 0, 0);
  };
  auto stB = [&](int d, int h, int s, int kt) {
    __builtin_amdgcn_global_load_lds(
        (const __attribute__((address_space(1))) void*)(bgp + (size_t)(h * 128 + s * 64) * 2048 + kt * 64),
        (__attribute__((address_space(3))) void*)(lb + d * 65536 + 32768 + h * 16384 + s * 8192 + tid * 16),
        16, 0, 0);
  };

  // Fragment read bases. Logical k-slot = ks*4+quad; phys colbyte = (slot^(lr&7))*16.
  const int c16_0 = ((quad) ^ (lr & 7)) * 16;
  const int c16_1 = ((4 + quad) ^ (lr & 7)) * 16;
  const char* pAb = lb + wm * 16384 + lr * 128;  // +d*65536 + rowoff*128 + c16
  const char* pBb = lb + 32768 + (wn >> 1) * 16384 + ((wn & 1) * 64 + lr) * 128;

  floatx4 acc[8][4] = {};
  short8 fa[4][2], fb0[2][2], fb1[2][2];

  // Prologue: stage K-tile 0 into buf 0 (8 issues), drain, barrier.
  stA(0, 0, 0, 0); stA(0, 0, 1, 0); stA(0, 1, 0, 0); stA(0, 1, 1, 0);
  stB(0, 0, 0, 0); stB(0, 0, 1, 0); stB(0, 1, 0, 0); stB(0, 1, 1, 0);
  asm volatile("s_waitcnt vmcnt(0)" ::: "memory");
  BAR();

  for (int t = 0; t < 32; ++t) {
    const int d = t & 1, dn = d ^ 1;
    const char* pA = pAb + d * 65536;
    const char* pB = pBb + d * 65536;
    const bool st = (t < 31);
    const int kt1 = t + 1;

    // ---- P1: read A(mh0) 8 + B(nh0) 4; stage t+1 A halves ----
#pragma unroll
    for (int mi = 0; mi < 4; ++mi) {
      fa[mi][0] = *(const short8*)(pA + (mi * 16) * 128 + c16_0);
      fa[mi][1] = *(const short8*)(pA + (mi * 16) * 128 + c16_1);
    }
#pragma unroll
    for (int ni = 0; ni < 2; ++ni) {
      fb0[ni][0] = *(const short8*)(pB + (ni * 16) * 128 + c16_0);
      fb0[ni][1] = *(const short8*)(pB + (ni * 16) * 128 + c16_1);
    }
    if (st) { stA(dn, 0, 0, kt1); stA(dn, 0, 1, kt1); stA(dn, 1, 0, kt1); stA(dn, 1, 1, kt1); }
    BAR();
    asm volatile("s_waitcnt lgkmcnt(0)" ::: "memory");
    __builtin_amdgcn_s_setprio(1);
#pragma unroll
    for (int mi = 0; mi < 4; ++mi)
#pragma unroll
      for (int ni = 0; ni < 2; ++ni) {
        acc[mi][ni] = MFMA16(fa[mi][0], fb0[ni][0], acc[mi][ni]);
        acc[mi][ni] = MFMA16(fa[mi][1], fb0[ni][1], acc[mi][ni]);
      }
    __builtin_amdgcn_s_setprio(0);
    BAR();

    // ---- P2: read B(nh1) 4; stage t+1 B halves ----
#pragma unroll
    for (int ni = 0; ni < 2; ++ni) {
      fb1[ni][0] = *(const short8*)(pB + (32 + ni * 16) * 128 + c16_0);
      fb1[ni][1] = *(const short8*)(pB + (32 + ni * 16) * 128 + c16_1);
    }
    if (st) { stB(dn, 0, 0, kt1); stB(dn, 0, 1, kt1); stB(dn, 1, 0, kt1); stB(dn, 1, 1, kt1); }
    BAR();
    asm volatile("s_waitcnt lgkmcnt(0)" ::: "memory");
    __builtin_amdgcn_s_setprio(1);
#pragma unroll
    for (int mi = 0; mi < 4; ++mi)
#pragma unroll
      for (int ni = 0; ni < 2; ++ni) {
        acc[mi][2 + ni] = MFMA16(fa[mi][0], fb1[ni][0], acc[mi][2 + ni]);
        acc[mi][2 + ni] = MFMA16(fa[mi][1], fb1[ni][1], acc[mi][2 + ni]);
      }
    __builtin_amdgcn_s_setprio(0);
    BAR();

    // ---- P3: read A(mh1) 8; drain t+1's A stages (issued P1, 2 phases old) ----
#pragma unroll
    for (int mi = 0; mi < 4; ++mi) {
      fa[mi][0] = *(const short8*)(pA + (64 + mi * 16) * 128 + c16_0);
      fa[mi][1] = *(const short8*)(pA + (64 + mi * 16) * 128 + c16_1);
    }
    if (st) asm volatile("s_waitcnt vmcnt(4)" ::: "memory");
    BAR();
    asm volatile("s_waitcnt lgkmcnt(0)" ::: "memory");
    __builtin_amdgcn_s_setprio(1);
#pragma unroll
    for (int mi = 0; mi < 4; ++mi)
#pragma unroll
      for (int ni = 0; ni < 2; ++ni) {
        acc[4 + mi][2 + ni] = MFMA16(fa[mi][0], fb1[ni][0], acc[4 + mi][2 + ni]);
        acc[4 + mi][2 + ni] = MFMA16(fa[mi][1], fb1[ni][1], acc[4 + mi][2 + ni]);
      }
    __builtin_amdgcn_s_setprio(0);
    BAR();

    // ---- P4: no reads (fa from P3, fb0 kept from P1); drain t+1's B stages ----
    if (st) asm volatile("s_waitcnt vmcnt(0)" ::: "memory");
    BAR();
    __builtin_amdgcn_s_setprio(1);
#pragma unroll
    for (int mi = 0; mi < 4; ++mi)
#pragma unroll
      for (int ni = 0; ni < 2; ++ni) {
        acc[4 + mi][ni] = MFMA16(fa[mi][0], fb0[ni][0], acc[4 + mi][ni]);
        acc[4 + mi][ni] = MFMA16(fa[mi][1], fb0[ni][1], acc[4 + mi][ni]);
      }
    __builtin_amdgcn_s_setprio(0);
    BAR();
  }

  // ---- epilogue: LDS-staged, full-line stores ----
  float* ldsf = (float*)lds;                 // [32][268] fp32, stride 268
  __syncthreads();                           // drain K-loop LDS reads (all waves)

  float4 bv;
  {
    const float* bp = bias + n0 + l * 4;
    bv.x = bp[0]; bv.y = bp[1]; bv.z = bp[2]; bv.w = bp[3];
  }

#pragma unroll
  for (int a = 0; a < 8; ++a) {
    // fragment a: rows (wm*16 + quad*4 + r), cols (wn*64 + ni*16 + lr)
#pragma unroll
    for (int ni = 0; ni < 4; ++ni)
#pragma unroll
      for (int r = 0; r < 4; ++r)
        ldsf[(wm * 16 + quad * 4 + r) * 268 + wn * 64 + ni * 16 + lr] = acc[a][ni][r];
    __syncthreads();

    const int rbase = m0 + (a >> 2) * 64 + (a & 3) * 16;
#pragma unroll
    for (int it = 0; it < 4; ++it) {
      const int row32 = w * 4 + it;                       // 0..31
      const int grow = rbase + (row32 >> 4) * 128 + (row32 & 15);
      float4 f = *(const float4*)&ldsf[row32 * 268 + l * 4];
      f.x += bv.x; f.y += bv.y; f.z += bv.z; f.w += bv.w;
      if (n0 < 2048) {
        *(ushort4*)(qb + (size_t)grow * 2048 + n0 + l * 4) =
            f4bf(fmaxf(f.x, 0.f) * RSQRT_DH, fmaxf(f.y, 0.f) * RSQRT_DH,
                 fmaxf(f.z, 0.f) * RSQRT_DH, fmaxf(f.w, 0.f) * RSQRT_DH);
      } else if (n0 < 3072) {
        float sx = fminf(1.f / (1.f + __expf(-f.x)), 0.95f);
        float sy = fminf(1.f / (1.f + __expf(-f.y)), 0.95f);
        float sz = fminf(1.f / (1.f + __expf(-f.z)), 0.95f);
        float sw = fminf(1.f / (1.f + __expf(-f.w)), 0.95f);
        size_t idx = (size_t)grow * 1024 + (n0 - 2048) + l * 4;
        *(ushort4*)(kb + idx) = f4bf(sx, sy, sz, sw);
        float4 g4; g4.x = log1pf(-sx); g4.y = log1pf(-sy);
        g4.z = log1pf(-sz); g4.w = log1pf(-sw);
        *(float4*)(gf + idx) = g4;
      } else {
        *(ushort4*)(vb + (size_t)grow * 1024 + (n0 - 3072) + l * 4) =
            f4bf(f.x, f.y, f.z, f.w);
      }
    }
    if (a < 7) __syncthreads();   // protect next pass's LDS overwrite
  }
}

// Parallel inclusive cumsum over rows of sBc[64][128] (Hillis-Steele, float4).
// Replaces the 128-thread serial 64-iteration dependent chain (~9.6k cy).
static __device__ __forceinline__ void scan64x128(float* sBc, int t) {
  float4* x4 = (float4*)sBc;   // 2048 float4: e = row*32 + c4
#pragma unroll
  for (int s = 1; s < 64; s <<= 1) {
    const int off = s * 32;
    float4 a[8];
#pragma unroll
    for (int j = 0; j < 8; ++j) {
      int e = j * 256 + t;
      if (e >= off) {
        float4 cu = x4[e];
        float4 pr = x4[e - off];
        a[j].x = cu.x + pr.x; a[j].y = cu.y + pr.y;
        a[j].z = cu.z + pr.z; a[j].w = cu.w + pr.w;
      }
    }
    __syncthreads();
#pragma unroll
    for (int j = 0; j < 8; ++j) {
      int e = j * 256 + t;
      if (e >= off) x4[e] = a[j];
    }
    __syncthreads();
  }
}

// ---------------- K3: per-chunk P = kg^T @ v and b_last; grid (chunk=32, chain=64)
__launch_bounds__(256)
__global__ void k_phaseA(const unsigned short* __restrict__ kb,
                         const unsigned short* __restrict__ vb,
                         const float* __restrict__ gf,
                         float* __restrict__ blast,
                         unsigned short* __restrict__ Pb) {
  __shared__ float sBc[64 * 128];
  __shared__ float sKg[64 * 128];
  const int t = threadIdx.x;
  const int chunk = blockIdx.x, chain = blockIdx.y;
  const int b = chain >> 4, h = chain & 15, kvh = h >> 1;
  const int t0 = b * 2048 + chunk * 64;

#pragma unroll
  for (int rep = 0; rep < 8; ++rep) {
    int e = rep * 256 + t;
    int i = e >> 5, d4 = e & 31;
    *(float4*)(sBc + i * 128 + d4 * 4) =
        *(const float4*)(gf + (size_t)(t0 + i) * 1024 + kvh * 128 + d4 * 4);
  }
  __syncthreads();
  scan64x128(sBc, t);
  if (t < 128) blast[((size_t)chain * 32 + chunk) * 128 + t] = sBc[63 * 128 + t];
#pragma unroll
  for (int rep = 0; rep < 32; ++rep) {
    int e = rep * 256 + t;
    int i = e >> 7, d = e & 127;
    float kk = bf2f(kb[(size_t)(t0 + i) * 1024 + kvh * 128 + d]);
    sKg[e] = kk * __expf(sBc[63 * 128 + d] - sBc[e]);
  }
  __syncthreads();
  const int kq = t >> 3, vq = t & 7;
  const int kd0 = kq * 4, vd0 = vq * 16;
  float acc[4][16] = {};
  const unsigned short* vrow = vb + (size_t)t0 * 1024 + kvh * 128 + vd0;
  for (int i = 0; i < 64; ++i) {
    float4 kg4 = *(const float4*)(sKg + i * 128 + kd0);
    float ka[4] = {kg4.x, kg4.y, kg4.z, kg4.w};
    ushort4 v0 = *(const ushort4*)(vrow + (size_t)i * 1024);
    ushort4 v1 = *(const ushort4*)(vrow + (size_t)i * 1024 + 4);
    ushort4 v2 = *(const ushort4*)(vrow + (size_t)i * 1024 + 8);
    ushort4 v3 = *(const ushort4*)(vrow + (size_t)i * 1024 + 12);
    float vf[16] = {bf2f(v0.x), bf2f(v0.y), bf2f(v0.z), bf2f(v0.w),
                    bf2f(v1.x), bf2f(v1.y), bf2f(v1.z), bf2f(v1.w),
                    bf2f(v2.x), bf2f(v2.y), bf2f(v2.z), bf2f(v2.w),
                    bf2f(v3.x), bf2f(v3.y), bf2f(v3.z), bf2f(v3.w)};
#pragma unroll
    for (int r = 0; r < 4; ++r)
#pragma unroll
      for (int j = 0; j < 16; ++j) acc[r][j] += ka[r] * vf[j];
  }
  size_t pbase = ((size_t)chain * 32 + chunk) * 16384;
#pragma unroll
  for (int r = 0; r < 4; ++r)
#pragma unroll
    for (int j4 = 0; j4 < 4; ++j4)
      *(ushort4*)(Pb + pbase + (size_t)(kd0 + r) * 128 + vd0 + j4 * 4) =
          f4bf(acc[r][j4 * 4], acc[r][j4 * 4 + 1], acc[r][j4 * 4 + 2], acc[r][j4 * 4 + 3]);
}

// ---------------- K4: state scan, S checkpoints (state at chunk START), grid (16, 64)
__launch_bounds__(256)
__global__ void k_scan(const float* __restrict__ kv_cache,
                       const int* __restrict__ sidx,
                       const float* __restrict__ blast,
                       const unsigned short* __restrict__ Pb,
                       unsigned short* __restrict__ Sb) {
  const int t = threadIdx.x;
  const int part = blockIdx.x;
  const int chain = blockIdx.y;
  const int b = chain >> 4, h = chain & 15;
  const int e0 = part * 1024 + t * 4;
  const int kd = e0 >> 7;
  const int slot = sidx[b];
  float4 s = *(const float4*)(kv_cache + ((size_t)slot * 16 + h) * 16384 + e0);
#pragma unroll 1
  for (int c = 0; c < 32; ++c) {
    *(ushort4*)(Sb + ((size_t)c * 64 + chain) * 16384 + e0) = f4bf(s.x, s.y, s.z, s.w);
    float eb = __expf(blast[((size_t)chain * 32 + c) * 128 + kd]);
    ushort4 p = *(const ushort4*)(Pb + ((size_t)chain * 32 + c) * 16384 + e0);
    s.x = s.x * eb + bf2f(p.x);
    s.y = s.y * eb + bf2f(p.y);
    s.z = s.z * eb + bf2f(p.z);
    s.w = s.w * eb + bf2f(p.w);
  }
}

// ---------------- K5 (MFMA rewrite): o = qe@S + (masked A)@v ; grid (chunk=32, chain=64)
// Sub-block factorization: for i-block I (16 rows), reference R_I[k]=Bc[16I-1][k]:
//   A_ij = (q_i e^{Bc_i-R_I}) . (k_j e^{R_I-Bc_j}),  exponents bounded by +/-48.
__launch_bounds__(256)
__global__ void k_output(const unsigned short* __restrict__ qb,
                         const unsigned short* __restrict__ kb,
                         const unsigned short* __restrict__ vb,
                         const float* __restrict__ gf,
                         const unsigned short* __restrict__ Sb,
                         float* __restrict__ out) {
  __shared__ float sBc[64 * 128];              // 32 KB, live whole kernel
  __shared__ unsigned short sR3[11136];        // 22272 B, phase-overlaid
  unsigned short* sA   = sR3;                  // [64][72]  (ph4 out, ph5 in)
  unsigned short* sKE  = sR3 + 4608;           // [32][136] (ph4)
  unsigned short* sQE2 = sR3 + 4608 + 4352;    // [16][136] (ph4)
  unsigned short* sQE0 = sR3;                  // [64][72]  (ph3, aliases sA)
  unsigned short* sSt  = sR3 + 4608;           // [64][76]  (ph3, aliases sKE)
  unsigned short* sVt  = sR3 + 4608;           // [64][76]  (ph5, aliases sKE)

  const int t = threadIdx.x;
  const int w = t >> 6, l = t & 63;
  const int lr = l & 15, quad = l >> 4;
  const int chunk = blockIdx.x, chain = blockIdx.y;
  const int b = chain >> 4, h = chain & 15, kvh = h >> 1;
  const int t0 = b * 2048 + chunk * 64;
  const size_t sbase = ((size_t)chunk * 64 + chain) * 16384;

  // ---- ph1: Bc = cumsum(g) ----
#pragma unroll
  for (int rep = 0; rep < 8; ++rep) {
    int e = rep * 256 + t, i = e >> 5, d4 = e & 31;
    *(float4*)(sBc + i * 128 + d4 * 4) =
        *(const float4*)(gf + (size_t)(t0 + i) * 1024 + kvh * 128 + d4 * 4);
  }
  __syncthreads();
  scan64x128(sBc, t);

  floatx4 o[8];
#pragma unroll
  for (int i = 0; i < 8; ++i) o[i] = 0.f;

  // ---- ph3: o_inter = (q*exp(Bc)) @ S, k- and v-halved ----
#pragma unroll
  for (int kh = 0; kh < 2; ++kh) {
    __syncthreads();
    // stage QE0: 64 rows x 64 k (k-half), stride 72
#pragma unroll
    for (int rep = 0; rep < 2; ++rep) {
      int idx = rep * 256 + t;
      int i = idx >> 3, g = idx & 7;
      int k0 = kh * 64 + g * 8;
      short8 q8 = *(const short8*)(qb + (size_t)(t0 + i) * 2048 + h * 128 + k0);
      short8 r;
#pragma unroll
      for (int u = 0; u < 8; ++u)
        r[u] = (short)f2bf(bf2f((unsigned short)q8[u]) * __expf(sBc[i * 128 + k0 + u]));
      *(short8*)(sQE0 + i * 72 + g * 8) = r;
    }
#pragma unroll
    for (int vh = 0; vh < 2; ++vh) {
      __syncthreads();
      // stage St' = S^T half: [v_local 64][k_local 64] stride 76
#pragma unroll
      for (int rep = 0; rep < 2; ++rep) {
        int idx = rep * 256 + t;
        int kl = idx >> 3, g = idx & 7;
        short8 s8 = *(const short8*)(Sb + sbase + (size_t)(kh * 64 + kl) * 128 + vh * 64 + g * 8);
#pragma unroll
        for (int u = 0; u < 8; ++u) sSt[(g * 8 + u) * 76 + kl] = (unsigned short)s8[u];
      }
      __syncthreads();
      short8 af0 = *(const short8*)(sQE0 + (w * 16 + lr) * 72 + quad * 8);
      short8 af1 = *(const short8*)(sQE0 + (w * 16 + lr) * 72 + 32 + quad * 8);
#pragma unroll
      for (int tv = 0; tv < 4; ++tv) {
        const unsigned short* bp = sSt + (tv * 16 + lr) * 76 + quad * 8;
        short8 bf0 = ld8u(bp);
        short8 bf1 = ld8u(bp + 32);
        o[vh * 4 + tv] = MFMA16(af0, bf0, o[vh * 4 + tv]);
        o[vh * 4 + tv] = MFMA16(af1, bf1, o[vh * 4 + tv]);
      }
    }
  }

  // ---- ph4: A (masked, factorized), into sA bf16 [64][72] ----
  __syncthreads();
  for (int idx = t; idx < 576; idx += 256)
    *(short8*)(sA + idx * 8) = (short8)0;
#pragma unroll
  for (int I = 0; I < 4; ++I) {
    const float* Rrow = (I > 0) ? (sBc + (I * 16 - 1) * 128) : nullptr;
    for (int base = 0; base < (I + 1) * 16; base += 32) {
      int nrows = min(32, (I + 1) * 16 - base);
      __syncthreads();
      // stage KE_I rows [base, base+nrows), full k=128, stride 136
      int ngroups = nrows * 16;
      for (int idx = t; idx < ngroups; idx += 256) {
        int jl = idx >> 4, g = idx & 15;
        int j = base + jl, k0 = g * 8;
        short8 k8 = *(const short8*)(kb + (size_t)(t0 + j) * 1024 + kvh * 128 + k0);
        short8 r;
#pragma unroll
        for (int u = 0; u < 8; ++u) {
          int k = k0 + u;
          float Rk = Rrow ? Rrow[k] : 0.f;
          r[u] = (short)f2bf(bf2f((unsigned short)k8[u]) * __expf(Rk - sBc[j * 128 + k]));
        }
        *(short8*)(sKE + jl * 136 + k0) = r;
      }
      if (base == 0) {
        // stage QE2_I: 16 rows, shifted by R_I
        {
          int idx = t;  // exactly 256 groups
          int il = idx >> 4, g = idx & 15;
          int i = I * 16 + il, k0 = g * 8;
          short8 q8 = *(const short8*)(qb + (size_t)(t0 + i) * 2048 + h * 128 + k0);
          short8 r;
#pragma unroll
          for (int u = 0; u < 8; ++u) {
            int k = k0 + u;
            float Rk = Rrow ? Rrow[k] : 0.f;
            r[u] = (short)f2bf(bf2f((unsigned short)q8[u]) * __expf(sBc[i * 128 + k] - Rk));
          }
          *(short8*)(sQE2 + il * 136 + k0) = r;
        }
      }
      __syncthreads();
      const int J = w;
      if (J * 16 >= base && J * 16 < base + nrows) {
        floatx4 a4 = {};
#pragma unroll
        for (int ks = 0; ks < 4; ++ks) {
          short8 afr = *(const short8*)(sQE2 + lr * 136 + ks * 32 + quad * 8);
          short8 bfr = *(const short8*)(sKE + (J * 16 - base + lr) * 136 + ks * 32 + quad * 8);
          a4 = MFMA16(afr, bfr, a4);
        }
#pragma unroll
        for (int r = 0; r < 4; ++r) {
          int il = quad * 4 + r;
          float v = ((J < I) || (lr <= il)) ? a4[r] : 0.f;
          sA[(I * 16 + il) * 72 + J * 16 + lr] = f2bf(v);
        }
      }
    }
  }

  // ---- ph5: o += A @ v, v-halved ----
  __syncthreads();
  short8 aA0 = *(const short8*)(sA + (w * 16 + lr) * 72 + quad * 8);
  short8 aA1 = *(const short8*)(sA + (w * 16 + lr) * 72 + 32 + quad * 8);
#pragma unroll
  for (int vh = 0; vh < 2; ++vh) {
    if (vh) __syncthreads();
    // stage Vt = v^T half: [vd_local 64][j 64] stride 76
#pragma unroll
    for (int rep = 0; rep < 2; ++rep) {
      int idx = rep * 256 + t;
      int j = idx >> 3, g = idx & 7;
      short8 v8 = *(const short8*)(vb + (size_t)(t0 + j) * 1024 + kvh * 128 + vh * 64 + g * 8);
#pragma unroll
      for (int u = 0; u < 8; ++u) sVt[(g * 8 + u) * 76 + j] = (unsigned short)v8[u];
    }
    __syncthreads();
#pragma unroll
    for (int tv = 0; tv < 4; ++tv) {
      const unsigned short* bp = sVt + (tv * 16 + lr) * 76 + quad * 8;
      short8 b0 = ld8u(bp);
      short8 b1 = ld8u(bp + 32);
      o[vh * 4 + tv] = MFMA16(aA0, b0, o[vh * 4 + tv]);
      o[vh * 4 + tv] = MFMA16(aA1, b1, o[vh * 4 + tv]);
    }
  }

  // ---- epilogue: D layout row=quad*4+r, col=lr ----
#pragma unroll
  for (int tv8 = 0; tv8 < 8; ++tv8) {
    int col = (tv8 >> 2) * 64 + (tv8 & 3) * 16 + lr;
#pragma unroll
    for (int r = 0; r < 4; ++r) {
      int i = w * 16 + quad * 4 + r;
      out[(size_t)(t0 + i) * 2048 + h * 128 + col] = o[tv8][r];
    }
  }
}

extern "C" void kernel_launch(void* const* d_in, const int* in_sizes, int n_in,
                              void* d_out, int out_size, void* d_ws, size_t ws_size,
                              hipStream_t stream) {
  (void)in_sizes; (void)n_in; (void)out_size; (void)ws_size;
  const float* hs   = (const float*)d_in[0];
  const float* W    = (const float*)d_in[1];
  const float* bias = (const float*)d_in[2];
  const float* kvc  = (const float*)d_in[3];
  const int*   sidx = (const int*)d_in[4];

  char* ws = (char*)d_ws;
  unsigned short* Sb  = (unsigned short*)(ws + 0);          // 67 MB (aliases hsb/wtb, dead after gemm)
  unsigned short* hsb = (unsigned short*)(ws + 0);
  unsigned short* wtb = (unsigned short*)(ws + 33554432);
  unsigned short* qb  = (unsigned short*)(ws + 67108864);
  unsigned short* kb  = (unsigned short*)(ws + 100663296);
  unsigned short* vb  = (unsigned short*)(ws + 117440512);
  float*          gf  = (float*)(ws + 134217728);
  float*          bl  = (float*)(ws + 167772160);
  unsigned short* Pb  = (unsigned short*)d_out;             // staged in d_out, consumed by k_scan
  float* out = (float*)d_out;

  k_cvt<<<dim3(16384), dim3(256), 0, stream>>>(hs, hsb, 16777216 / 4);
  k_cvt_wt<<<dim3(128, 64), dim3(256), 0, stream>>>(W, wtb);
  k_gemm<<<dim3(512), dim3(512), 0, stream>>>(hsb, wtb, bias, qb, kb, vb, gf);
  k_phaseA<<<dim3(32, 64), dim3(256), 0, stream>>>(kb, vb, gf, bl, Pb);
  k_scan<<<dim3(16, 64), dim3(256), 0, stream>>>(kvc, sidx, bl, Pb, Sb);
  k_output<<<dim3(32, 64), dim3(256), 0, stream>>>(qb, kb, vb, gf, Sb, out);
}

// Round 7
// 563.354 us; speedup vs baseline: 1.0762x; 1.0762x over previous
//
#include <hip/hip_runtime.h>
#include <hip/hip_bf16.h>
#include <math.h>

// Problem constants
//  D=2048, H=16, KVH=8, DH=128, B=4, L=2048, T=8192, C=64, chunks=32, chains=B*H=64
#define RSQRT_DH 0.08838834764831845f

typedef __attribute__((ext_vector_type(8))) short short8;
typedef __attribute__((ext_vector_type(4))) float floatx4;

#define MFMA16(a, b, c) __builtin_amdgcn_mfma_f32_16x16x32_bf16((a), (b), (c), 0, 0, 0)

static __device__ __forceinline__ float bf2f(unsigned short u) {
  return __uint_as_float(((unsigned int)u) << 16);
}
static __device__ __forceinline__ unsigned short f2bf(float f) {
  unsigned int x = __float_as_uint(f);
  return (unsigned short)((x + 0x7fffu + ((x >> 16) & 1u)) >> 16);
}
static __device__ __forceinline__ ushort4 f4bf(float a, float b, float c, float d) {
  ushort4 r; r.x = f2bf(a); r.y = f2bf(b); r.z = f2bf(c); r.w = f2bf(d); return r;
}
// 8-byte-aligned LDS load of 8 bf16 (for stride-76 buffers)
static __device__ __forceinline__ short8 ld8u(const unsigned short* p) {
  short4 a = *(const short4*)p;
  short4 b = *(const short4*)(p + 4);
  short8 r;
  r[0] = a.x; r[1] = a.y; r[2] = a.z; r[3] = a.w;
  r[4] = b.x; r[5] = b.y; r[6] = b.z; r[7] = b.w;
  return r;
}

// ---------------- K0: fp32 -> bf16 convert (hidden_states) ----------------
__launch_bounds__(256)
__global__ void k_cvt(const float* __restrict__ in, unsigned short* __restrict__ out, int n4) {
  int i = blockIdx.x * 256 + threadIdx.x;
  if (i >= n4) return;
  float4 v = ((const float4*)in)[i];
  ((ushort4*)out)[i] = f4bf(v.x, v.y, v.z, v.w);
}

// ---------------- K1: W (2048 x 4096 f32) -> Wt (4096 x 2048 bf16), transposed
__launch_bounds__(256)
__global__ void k_cvt_wt(const float* __restrict__ W, unsigned short* __restrict__ Wt) {
  __shared__ float tile[32][33];
  int t = threadIdx.x;
  int c = t & 31, r = t >> 5;            // r in 0..7
  int bx = blockIdx.x, by = blockIdx.y;  // bx: n-tile, by: k-tile
#pragma unroll
  for (int j = 0; j < 4; ++j)
    tile[r + j * 8][c] = W[(size_t)(by * 32 + r + j * 8) * 4096 + bx * 32 + c];
  __syncthreads();
#pragma unroll
  for (int j = 0; j < 4; ++j)
    Wt[(size_t)(bx * 32 + r + j * 8) * 2048 + by * 32 + c] = f2bf(tile[c][r + j * 8]);
}

// ---------------- K2: bf16 MFMA GEMM, m97 structure + swizzle + TLP
//  M=8192 N=4096 K=2048, fused activations.
//  128x128 tile, BK=64, 256 threads = 4 waves (2M x 2N), per-wave 64x64
//  (acc[4][4]). Single 32KB LDS buffer, plain 2-syncthreads K-loop (compiler
//  inserts the vmcnt(0) drain). The pipelining comes from TLP: 4 blocks/CU
//  (launch_bounds (256,4)); one block's MFMA covers another's staging/drain
//  (m114 mechanism). Rounds 4-6 proved intra-block scheduling is NOT the
//  lever at 1 block/CU (3 schedules, all ~230us / 25% MfmaUtil).
//  Bank swizzle (rounds 2-6, measured 0 conflicts): LDS row = 128B, 8 slots
//  of 16B; phys slot = logical ^ (row&7), applied on BOTH sides (pre-swizzled
//  global source + swizzled ds_read) per rule 21.
//  Epilogue: LDS-staged full-line stores (round-4: WRITE_SIZE 360->96MB).
__launch_bounds__(256, 4)
__global__ void k_gemm(const unsigned short* __restrict__ A,
                       const unsigned short* __restrict__ Bt,
                       const float* __restrict__ bias,
                       unsigned short* __restrict__ qb,
                       unsigned short* __restrict__ kb,
                       unsigned short* __restrict__ vb,
                       float* __restrict__ gf) {
  __shared__ unsigned short lds[16384];  // 32 KiB: A [128][64] + B [128][64]
  char* lb = (char*)lds;

  const int t = threadIdx.x;
  const int w = t >> 6, l = t & 63;
  const int wr = w >> 1, wc = w & 1;
  const int lr = l & 15, quad = l >> 4;

  // XCD-aware bijective chunking: 2048 blocks, id%8 = XCD, 16bm x 16bn per
  // XCD; within a chunk consecutive blocks walk bn (share the A panel in L2).
  const int id = blockIdx.x;
  const int x = id & 7, loc = id >> 3;               // loc 0..255
  const int bm = (x >> 1) * 16 + (loc >> 4);         // 0..63
  const int bn = (x & 1) * 16 + (loc & 15);          // 0..31
  const int m0 = bm * 128, n0 = bn * 128;

  // Staging: one global_load_lds issue = 256 threads x 16B = 4KB = 32 rows x
  // 128B. thread t -> row t>>3, LDS slot t&7; global slot = (t&7)^(row&7).
  const int srow = t >> 3;                           // 0..31
  const int sslot = (t & 7) ^ (srow & 7);
  const unsigned short* agp = A + (size_t)(m0 + srow) * 2048 + sslot * 8;
  const unsigned short* bgp = Bt + (size_t)(n0 + srow) * 2048 + sslot * 8;

  // Fragment reads: logical k-slot = ks*4+quad, phys = logical ^ (lr&7)
  // (row = mult-of-16 + lr -> row&7 == lr&7).
  const int c16_0 = ((quad) ^ (lr & 7)) * 16;
  const int c16_1 = ((4 + quad) ^ (lr & 7)) * 16;
  const char* pA = lb + wr * 8192 + lr * 128;            // + ti*2048 + c16
  const char* pB = lb + 16384 + wc * 8192 + lr * 128;    // + tj*2048 + c16

  floatx4 acc[4][4] = {};

  for (int kt = 0; kt < 32; ++kt) {
    __syncthreads();   // protect previous tile's LDS reads
#pragma unroll
    for (int it = 0; it < 4; ++it) {
      __builtin_amdgcn_global_load_lds(
          (const __attribute__((address_space(1))) void*)(agp + (size_t)it * 65536 + kt * 64),
          (__attribute__((address_space(3))) void*)(lb + it * 4096 + t * 16),
          16, 0, 0);
      __builtin_amdgcn_global_load_lds(
          (const __attribute__((address_space(1))) void*)(bgp + (size_t)it * 65536 + kt * 64),
          (__attribute__((address_space(3))) void*)(lb + 16384 + it * 4096 + t * 16),
          16, 0, 0);
    }
    __syncthreads();   // compiler drains vmcnt(0) -> tile resident
#pragma unroll
    for (int ks = 0; ks < 2; ++ks) {
      const int c16 = ks ? c16_1 : c16_0;
      short8 af[4], bf[4];
#pragma unroll
      for (int i = 0; i < 4; ++i) af[i] = *(const short8*)(pA + i * 2048 + c16);
#pragma unroll
      for (int i = 0; i < 4; ++i) bf[i] = *(const short8*)(pB + i * 2048 + c16);
#pragma unroll
      for (int ti = 0; ti < 4; ++ti)
#pragma unroll
        for (int tj = 0; tj < 4; ++tj)
          acc[ti][tj] = MFMA16(af[ti], bf[tj], acc[ti][tj]);
    }
  }

  // ---- epilogue: LDS-staged, full-line stores (4 passes of 32x128 fp32) ----
  float* ldsf = (float*)lds;                 // [32][132] fp32, 16.9 KB
  __syncthreads();                           // drain K-loop LDS reads

  const int c4 = (t & 31) * 4;
  float4 bv = *(const float4*)(bias + n0 + c4);

#pragma unroll
  for (int p = 0; p < 4; ++p) {
    // pass p: rows {wr*64 + p*16 + (quad*4+r)}, staged at ri = wr*16+quad*4+r
#pragma unroll
    for (int tj = 0; tj < 4; ++tj)
#pragma unroll
      for (int r = 0; r < 4; ++r)
        ldsf[(wr * 16 + quad * 4 + r) * 132 + wc * 64 + tj * 16 + lr] = acc[p][tj][r];
    __syncthreads();
#pragma unroll
    for (int it = 0; it < 4; ++it) {
      const int row32 = it * 8 + (t >> 5);            // 0..31
      const int grow = m0 + (row32 >> 4) * 64 + p * 16 + (row32 & 15);
      float4 f = *(const float4*)&ldsf[row32 * 132 + c4];
      f.x += bv.x; f.y += bv.y; f.z += bv.z; f.w += bv.w;
      if (n0 < 2048) {
        *(ushort4*)(qb + (size_t)grow * 2048 + n0 + c4) =
            f4bf(fmaxf(f.x, 0.f) * RSQRT_DH, fmaxf(f.y, 0.f) * RSQRT_DH,
                 fmaxf(f.z, 0.f) * RSQRT_DH, fmaxf(f.w, 0.f) * RSQRT_DH);
      } else if (n0 < 3072) {
        float sx = fminf(1.f / (1.f + __expf(-f.x)), 0.95f);
        float sy = fminf(1.f / (1.f + __expf(-f.y)), 0.95f);
        float sz = fminf(1.f / (1.f + __expf(-f.z)), 0.95f);
        float sw = fminf(1.f / (1.f + __expf(-f.w)), 0.95f);
        size_t idx = (size_t)grow * 1024 + (n0 - 2048) + c4;
        *(ushort4*)(kb + idx) = f4bf(sx, sy, sz, sw);
        float4 g4; g4.x = log1pf(-sx); g4.y = log1pf(-sy);
        g4.z = log1pf(-sz); g4.w = log1pf(-sw);
        *(float4*)(gf + idx) = g4;
      } else {
        *(ushort4*)(vb + (size_t)grow * 1024 + (n0 - 3072) + c4) =
            f4bf(f.x, f.y, f.z, f.w);
      }
    }
    __syncthreads();   // protect next pass's LDS overwrite
  }
}

// Parallel inclusive cumsum over rows of sBc[64][128] (Hillis-Steele, float4).
// Replaces the 128-thread serial 64-iteration dependent chain (~9.6k cy).
static __device__ __forceinline__ void scan64x128(float* sBc, int t) {
  float4* x4 = (float4*)sBc;   // 2048 float4: e = row*32 + c4
#pragma unroll
  for (int s = 1; s < 64; s <<= 1) {
    const int off = s * 32;
    float4 a[8];
#pragma unroll
    for (int j = 0; j < 8; ++j) {
      int e = j * 256 + t;
      if (e >= off) {
        float4 cu = x4[e];
        float4 pr = x4[e - off];
        a[j].x = cu.x + pr.x; a[j].y = cu.y + pr.y;
        a[j].z = cu.z + pr.z; a[j].w = cu.w + pr.w;
      }
    }
    __syncthreads();
#pragma unroll
    for (int j = 0; j < 8; ++j) {
      int e = j * 256 + t;
      if (e >= off) x4[e] = a[j];
    }
    __syncthreads();
  }
}

// ---------------- K3: per-chunk P = kg^T @ v and b_last; grid (chunk=32, chain=64)
__launch_bounds__(256)
__global__ void k_phaseA(const unsigned short* __restrict__ kb,
                         const unsigned short* __restrict__ vb,
                         const float* __restrict__ gf,
                         float* __restrict__ blast,
                         unsigned short* __restrict__ Pb) {
  __shared__ float sBc[64 * 128];
  __shared__ float sKg[64 * 128];
  const int t = threadIdx.x;
  const int chunk = blockIdx.x, chain = blockIdx.y;
  const int b = chain >> 4, h = chain & 15, kvh = h >> 1;
  const int t0 = b * 2048 + chunk * 64;

#pragma unroll
  for (int rep = 0; rep < 8; ++rep) {
    int e = rep * 256 + t;
    int i = e >> 5, d4 = e & 31;
    *(float4*)(sBc + i * 128 + d4 * 4) =
        *(const float4*)(gf + (size_t)(t0 + i) * 1024 + kvh * 128 + d4 * 4);
  }
  __syncthreads();
  scan64x128(sBc, t);
  if (t < 128) blast[((size_t)chain * 32 + chunk) * 128 + t] = sBc[63 * 128 + t];
#pragma unroll
  for (int rep = 0; rep < 32; ++rep) {
    int e = rep * 256 + t;
    int i = e >> 7, d = e & 127;
    float kk = bf2f(kb[(size_t)(t0 + i) * 1024 + kvh * 128 + d]);
    sKg[e] = kk * __expf(sBc[63 * 128 + d] - sBc[e]);
  }
  __syncthreads();
  const int kq = t >> 3, vq = t & 7;
  const int kd0 = kq * 4, vd0 = vq * 16;
  float acc[4][16] = {};
  const unsigned short* vrow = vb + (size_t)t0 * 1024 + kvh * 128 + vd0;
  for (int i = 0; i < 64; ++i) {
    float4 kg4 = *(const float4*)(sKg + i * 128 + kd0);
    float ka[4] = {kg4.x, kg4.y, kg4.z, kg4.w};
    ushort4 v0 = *(const ushort4*)(vrow + (size_t)i * 1024);
    ushort4 v1 = *(const ushort4*)(vrow + (size_t)i * 1024 + 4);
    ushort4 v2 = *(const ushort4*)(vrow + (size_t)i * 1024 + 8);
    ushort4 v3 = *(const ushort4*)(vrow + (size_t)i * 1024 + 12);
    float vf[16] = {bf2f(v0.x), bf2f(v0.y), bf2f(v0.z), bf2f(v0.w),
                    bf2f(v1.x), bf2f(v1.y), bf2f(v1.z), bf2f(v1.w),
                    bf2f(v2.x), bf2f(v2.y), bf2f(v2.z), bf2f(v2.w),
                    bf2f(v3.x), bf2f(v3.y), bf2f(v3.z), bf2f(v3.w)};
#pragma unroll
    for (int r = 0; r < 4; ++r)
#pragma unroll
      for (int j = 0; j < 16; ++j) acc[r][j] += ka[r] * vf[j];
  }
  size_t pbase = ((size_t)chain * 32 + chunk) * 16384;
#pragma unroll
  for (int r = 0; r < 4; ++r)
#pragma unroll
    for (int j4 = 0; j4 < 4; ++j4)
      *(ushort4*)(Pb + pbase + (size_t)(kd0 + r) * 128 + vd0 + j4 * 4) =
          f4bf(acc[r][j4 * 4], acc[r][j4 * 4 + 1], acc[r][j4 * 4 + 2], acc[r][j4 * 4 + 3]);
}

// ---------------- K4: state scan, S checkpoints (state at chunk START), grid (16, 64)
__launch_bounds__(256)
__global__ void k_scan(const float* __restrict__ kv_cache,
                       const int* __restrict__ sidx,
                       const float* __restrict__ blast,
                       const unsigned short* __restrict__ Pb,
                       unsigned short* __restrict__ Sb) {
  const int t = threadIdx.x;
  const int part = blockIdx.x;
  const int chain = blockIdx.y;
  const int b = chain >> 4, h = chain & 15;
  const int e0 = part * 1024 + t * 4;
  const int kd = e0 >> 7;
  const int slot = sidx[b];
  float4 s = *(const float4*)(kv_cache + ((size_t)slot * 16 + h) * 16384 + e0);
#pragma unroll 1
  for (int c = 0; c < 32; ++c) {
    *(ushort4*)(Sb + ((size_t)c * 64 + chain) * 16384 + e0) = f4bf(s.x, s.y, s.z, s.w);
    float eb = __expf(blast[((size_t)chain * 32 + c) * 128 + kd]);
    ushort4 p = *(const ushort4*)(Pb + ((size_t)chain * 32 + c) * 16384 + e0);
    s.x = s.x * eb + bf2f(p.x);
    s.y = s.y * eb + bf2f(p.y);
    s.z = s.z * eb + bf2f(p.z);
    s.w = s.w * eb + bf2f(p.w);
  }
}

// ---------------- K5 (MFMA rewrite): o = qe@S + (masked A)@v ; grid (chunk=32, chain=64)
// Sub-block factorization: for i-block I (16 rows), reference R_I[k]=Bc[16I-1][k]:
//   A_ij = (q_i e^{Bc_i-R_I}) . (k_j e^{R_I-Bc_j}),  exponents bounded by +/-48.
__launch_bounds__(256)
__global__ void k_output(const unsigned short* __restrict__ qb,
                         const unsigned short* __restrict__ kb,
                         const unsigned short* __restrict__ vb,
                         const float* __restrict__ gf,
                         const unsigned short* __restrict__ Sb,
                         float* __restrict__ out) {
  __shared__ float sBc[64 * 128];              // 32 KB, live whole kernel
  __shared__ unsigned short sR3[11136];        // 22272 B, phase-overlaid
  unsigned short* sA   = sR3;                  // [64][72]  (ph4 out, ph5 in)
  unsigned short* sKE  = sR3 + 4608;           // [32][136] (ph4)
  unsigned short* sQE2 = sR3 + 4608 + 4352;    // [16][136] (ph4)
  unsigned short* sQE0 = sR3;                  // [64][72]  (ph3, aliases sA)
  unsigned short* sSt  = sR3 + 4608;           // [64][76]  (ph3, aliases sKE)
  unsigned short* sVt  = sR3 + 4608;           // [64][76]  (ph5, aliases sKE)

  const int t = threadIdx.x;
  const int w = t >> 6, l = t & 63;
  const int lr = l & 15, quad = l >> 4;
  const int chunk = blockIdx.x, chain = blockIdx.y;
  const int b = chain >> 4, h = chain & 15, kvh = h >> 1;
  const int t0 = b * 2048 + chunk * 64;
  const size_t sbase = ((size_t)chunk * 64 + chain) * 16384;

  // ---- ph1: Bc = cumsum(g) ----
#pragma unroll
  for (int rep = 0; rep < 8; ++rep) {
    int e = rep * 256 + t, i = e >> 5, d4 = e & 31;
    *(float4*)(sBc + i * 128 + d4 * 4) =
        *(const float4*)(gf + (size_t)(t0 + i) * 1024 + kvh * 128 + d4 * 4);
  }
  __syncthreads();
  scan64x128(sBc, t);

  floatx4 o[8];
#pragma unroll
  for (int i = 0; i < 8; ++i) o[i] = 0.f;

  // ---- ph3: o_inter = (q*exp(Bc)) @ S, k- and v-halved ----
#pragma unroll
  for (int kh = 0; kh < 2; ++kh) {
    __syncthreads();
    // stage QE0: 64 rows x 64 k (k-half), stride 72
#pragma unroll
    for (int rep = 0; rep < 2; ++rep) {
      int idx = rep * 256 + t;
      int i = idx >> 3, g = idx & 7;
      int k0 = kh * 64 + g * 8;
      short8 q8 = *(const short8*)(qb + (size_t)(t0 + i) * 2048 + h * 128 + k0);
      short8 r;
#pragma unroll
      for (int u = 0; u < 8; ++u)
        r[u] = (short)f2bf(bf2f((unsigned short)q8[u]) * __expf(sBc[i * 128 + k0 + u]));
      *(short8*)(sQE0 + i * 72 + g * 8) = r;
    }
#pragma unroll
    for (int vh = 0; vh < 2; ++vh) {
      __syncthreads();
      // stage St' = S^T half: [v_local 64][k_local 64] stride 76
#pragma unroll
      for (int rep = 0; rep < 2; ++rep) {
        int idx = rep * 256 + t;
        int kl = idx >> 3, g = idx & 7;
        short8 s8 = *(const short8*)(Sb + sbase + (size_t)(kh * 64 + kl) * 128 + vh * 64 + g * 8);
#pragma unroll
        for (int u = 0; u < 8; ++u) sSt[(g * 8 + u) * 76 + kl] = (unsigned short)s8[u];
      }
      __syncthreads();
      short8 af0 = *(const short8*)(sQE0 + (w * 16 + lr) * 72 + quad * 8);
      short8 af1 = *(const short8*)(sQE0 + (w * 16 + lr) * 72 + 32 + quad * 8);
#pragma unroll
      for (int tv = 0; tv < 4; ++tv) {
        const unsigned short* bp = sSt + (tv * 16 + lr) * 76 + quad * 8;
        short8 bf0 = ld8u(bp);
        short8 bf1 = ld8u(bp + 32);
        o[vh * 4 + tv] = MFMA16(af0, bf0, o[vh * 4 + tv]);
        o[vh * 4 + tv] = MFMA16(af1, bf1, o[vh * 4 + tv]);
      }
    }
  }

  // ---- ph4: A (masked, factorized), into sA bf16 [64][72] ----
  __syncthreads();
  for (int idx = t; idx < 576; idx += 256)
    *(short8*)(sA + idx * 8) = (short8)0;
#pragma unroll
  for (int I = 0; I < 4; ++I) {
    const float* Rrow = (I > 0) ? (sBc + (I * 16 - 1) * 128) : nullptr;
    for (int base = 0; base < (I + 1) * 16; base += 32) {
      int nrows = min(32, (I + 1) * 16 - base);
      __syncthreads();
      // stage KE_I rows [base, base+nrows), full k=128, stride 136
      int ngroups = nrows * 16;
      for (int idx = t; idx < ngroups; idx += 256) {
        int jl = idx >> 4, g = idx & 15;
        int j = base + jl, k0 = g * 8;
        short8 k8 = *(const short8*)(kb + (size_t)(t0 + j) * 1024 + kvh * 128 + k0);
        short8 r;
#pragma unroll
        for (int u = 0; u < 8; ++u) {
          int k = k0 + u;
          float Rk = Rrow ? Rrow[k] : 0.f;
          r[u] = (short)f2bf(bf2f((unsigned short)k8[u]) * __expf(Rk - sBc[j * 128 + k]));
        }
        *(short8*)(sKE + jl * 136 + k0) = r;
      }
      if (base == 0) {
        // stage QE2_I: 16 rows, shifted by R_I
        {
          int idx = t;  // exactly 256 groups
          int il = idx >> 4, g = idx & 15;
          int i = I * 16 + il, k0 = g * 8;
          short8 q8 = *(const short8*)(qb + (size_t)(t0 + i) * 2048 + h * 128 + k0);
          short8 r;
#pragma unroll
          for (int u = 0; u < 8; ++u) {
            int k = k0 + u;
            float Rk = Rrow ? Rrow[k] : 0.f;
            r[u] = (short)f2bf(bf2f((unsigned short)q8[u]) * __expf(sBc[i * 128 + k] - Rk));
          }
          *(short8*)(sQE2 + il * 136 + k0) = r;
        }
      }
      __syncthreads();
      const int J = w;
      if (J * 16 >= base && J * 16 < base + nrows) {
        floatx4 a4 = {};
#pragma unroll
        for (int ks = 0; ks < 4; ++ks) {
          short8 afr = *(const short8*)(sQE2 + lr * 136 + ks * 32 + quad * 8);
          short8 bfr = *(const short8*)(sKE + (J * 16 - base + lr) * 136 + ks * 32 + quad * 8);
          a4 = MFMA16(afr, bfr, a4);
        }
#pragma unroll
        for (int r = 0; r < 4; ++r) {
          int il = quad * 4 + r;
          float v = ((J < I) || (lr <= il)) ? a4[r] : 0.f;
          sA[(I * 16 + il) * 72 + J * 16 + lr] = f2bf(v);
        }
      }
    }
  }

  // ---- ph5: o += A @ v, v-halved ----
  __syncthreads();
  short8 aA0 = *(const short8*)(sA + (w * 16 + lr) * 72 + quad * 8);
  short8 aA1 = *(const short8*)(sA + (w * 16 + lr) * 72 + 32 + quad * 8);
#pragma unroll
  for (int vh = 0; vh < 2; ++vh) {
    if (vh) __syncthreads();
    // stage Vt = v^T half: [vd_local 64][j 64] stride 76
#pragma unroll
    for (int rep = 0; rep < 2; ++rep) {
      int idx = rep * 256 + t;
      int j = idx >> 3, g = idx & 7;
      short8 v8 = *(const short8*)(vb + (size_t)(t0 + j) * 1024 + kvh * 128 + vh * 64 + g * 8);
#pragma unroll
      for (int u = 0; u < 8; ++u) sVt[(g * 8 + u) * 76 + j] = (unsigned short)v8[u];
    }
    __syncthreads();
#pragma unroll
    for (int tv = 0; tv < 4; ++tv) {
      const unsigned short* bp = sVt + (tv * 16 + lr) * 76 + quad * 8;
      short8 b0 = ld8u(bp);
      short8 b1 = ld8u(bp + 32);
      o[vh * 4 + tv] = MFMA16(aA0, b0, o[vh * 4 + tv]);
      o[vh * 4 + tv] = MFMA16(aA1, b1, o[vh * 4 + tv]);
    }
  }

  // ---- epilogue: D layout row=quad*4+r, col=lr ----
#pragma unroll
  for (int tv8 = 0; tv8 < 8; ++tv8) {
    int col = (tv8 >> 2) * 64 + (tv8 & 3) * 16 + lr;
#pragma unroll
    for (int r = 0; r < 4; ++r) {
      int i = w * 16 + quad * 4 + r;
      out[(size_t)(t0 + i) * 2048 + h * 128 + col] = o[tv8][r];
    }
  }
}

extern "C" void kernel_launch(void* const* d_in, const int* in_sizes, int n_in,
                              void* d_out, int out_size, void* d_ws, size_t ws_size,
                              hipStream_t stream) {
  (void)in_sizes; (void)n_in; (void)out_size; (void)ws_size;
  const float* hs   = (const float*)d_in[0];
  const float* W    = (const float*)d_in[1];
  const float* bias = (const float*)d_in[2];
  const float* kvc  = (const float*)d_in[3];
  const int*   sidx = (const int*)d_in[4];

  char* ws = (char*)d_ws;
  unsigned short* Sb  = (unsigned short*)(ws + 0);          // 67 MB (aliases hsb/wtb, dead after gemm)
  unsigned short* hsb = (unsigned short*)(ws + 0);
  unsigned short* wtb = (unsigned short*)(ws + 33554432);
  unsigned short* qb  = (unsigned short*)(ws + 67108864);
  unsigned short* kb  = (unsigned short*)(ws + 100663296);
  unsigned short* vb  = (unsigned short*)(ws + 117440512);
  float*          gf  = (float*)(ws + 134217728);
  float*          bl  = (float*)(ws + 167772160);
  unsigned short* Pb  = (unsigned short*)d_out;             // staged in d_out, consumed by k_scan
  float* out = (float*)d_out;

  k_cvt<<<dim3(16384), dim3(256), 0, stream>>>(hs, hsb, 16777216 / 4);
  k_cvt_wt<<<dim3(128, 64), dim3(256), 0, stream>>>(W, wtb);
  k_gemm<<<dim3(2048), dim3(256), 0, stream>>>(hsb, wtb, bias, qb, kb, vb, gf);
  k_phaseA<<<dim3(32, 64), dim3(256), 0, stream>>>(kb, vb, gf, bl, Pb);
  k_scan<<<dim3(16, 64), dim3(256), 0, stream>>>(kvc, sidx, bl, Pb, Sb);
  k_output<<<dim3(32, 64), dim3(256), 0, stream>>>(qb, kb, vb, gf, Sb, out);
}